// Round 20
// baseline (37.523 us; speedup 1.0000x reference)
//
#include <hip/hip_runtime.h>
#include <hip/hip_bf16.h>

// Problem constants
constexpr int   D      = 512;
constexpr float ALPHA  = 1.0f;
constexpr float EPS    = 1e-9f;
constexpr float INV_CNT = 1.0f / (32.0f * 128.0f * 128.0f);  // 1/524288

// ws layout (bytes)
constexpr size_t NRM_OFF  = 0;            // 8192*512*2 = 8388608 (bf16, k-major)
constexpr size_t PART_OFF = 8388608;      // 256*4
constexpr size_t CNT_OFF  = 8389632;      // int counter (memset to 0 each call)

typedef short bf16x8 __attribute__((ext_vector_type(8)));
typedef float f32x4  __attribute__((ext_vector_type(4)));

// round-to-nearest-even f32 -> bf16 bits
__device__ __forceinline__ short f2bf(float f) {
    unsigned u = __builtin_bit_cast(unsigned, f);
    unsigned r = (u + 0x7FFFu + ((u >> 16) & 1u)) >> 16;
    return (short)r;
}

// nrm2 layout (k-major, slot-rotated), written by k_normalize:
//   byte(b, ks, row, slot) = ((b*16 + ks)*256 + row)*64 + slot*16
//   chunk c of row r stored at slot (c + (r>>1)) & 3

// ---------------------------------------------------------------------------
// K1: row-normalize fp32 -> bf16 into k-major rotated layout.
// (byte-identical to rounds 17-19: XCD-co-located row assignment -- block p
// on XCD p&7 writes rows (p&7)*1024 + (p>>3)*4 ..+4, so batch b is produced
// on XCD b>>2, the same XCD that consumes it in k_fused. R17: -2.2us.)
__global__ __launch_bounds__(256) void k_normalize(const float* __restrict__ in,
                                                   short* __restrict__ nrm2) {
    const int wid  = threadIdx.x >> 6;
    const int lane = threadIdx.x & 63;
    const int p    = blockIdx.x;
    const int r    = (p & 7) * 1024 + (p >> 3) * 4 + wid;   // global row 0..8191
    const int b    = r >> 8;
    const int row  = r & 255;
    const float4* src = (const float4*)(in + (size_t)r * D);
    float4 x0 = src[2 * lane];
    float4 x1 = src[2 * lane + 1];
    float ss = x0.x*x0.x + x0.y*x0.y + x0.z*x0.z + x0.w*x0.w
             + x1.x*x1.x + x1.y*x1.y + x1.z*x1.z + x1.w*x1.w;
    #pragma unroll
    for (int o = 32; o > 0; o >>= 1) ss += __shfl_xor(ss, o, 64);
    const float inv = rsqrtf(ss);
    bf16x8 v;                                     // elems 8*lane .. 8*lane+7
    v[0] = f2bf(x0.x * inv); v[1] = f2bf(x0.y * inv);
    v[2] = f2bf(x0.z * inv); v[3] = f2bf(x0.w * inv);
    v[4] = f2bf(x1.x * inv); v[5] = f2bf(x1.y * inv);
    v[6] = f2bf(x1.z * inv); v[7] = f2bf(x1.w * inv);
    const int ks   = lane >> 2;                   // k-slice 0..15
    const int slot = ((lane & 3) + (row >> 1)) & 3;
    char* dst = (char*)nrm2 + ((((size_t)b * 16 + ks) * 256 + row) * 64 + slot * 16);
    *(bf16x8*)dst = v;
}

// ---------------------------------------------------------------------------
// K2: FUSED gram+loss+final-reduce. 256 blocks x 512 thr (8 waves).
// Gram+loss byte-identical to R19 (best: 29.2us, absmax 0). CHANGE (single
// variable): k_reduce merged in via last-block-done tail -- part[p] write,
// release fence, same-address atomicAdd (256 blocks: R8-verified benign
// scale; R11's pathology was 2048), last block sums 256 partials -> out[0].
// Removes one launch + a 1-block kernel's ramp (~1.5us).
constexpr int PSTR = 260;

__global__ __launch_bounds__(512, 2) void k_fused(const short* __restrict__ nrm2,
                                                  float* __restrict__ part,
                                                  int* __restrict__ counter,
                                                  float* __restrict__ out) {
    __shared__ __align__(16) char smem[33312];    // P 32x260 f32 = 33280; red @33280
    __shared__ int lastflag;

    const int p     = blockIdx.x;
    const int slot  = p >> 3;                     // 0..31
    const int b     = (p & 7) * 4 + (slot & 3);   // XCD-bijective: 4 batches/XCD
    const int chunk = slot >> 2;                  // 0..7
    const int w     = threadIdx.x >> 6;           // 0..7
    const int lane  = threadIdx.x & 63;
    const int fr    = lane & 15;
    const int kg    = lane >> 4;

    const char* batchbase = (const char*)nrm2 + (size_t)b * 16 * 256 * 64;

    // slot rotation: all row terms (chunk*16, +128, w*32, +16) vanish mod 4
    const int sigma = (kg + (fr >> 1)) & 3;

    // A: t-row chunk*16+fr and c-row 128+chunk*16+fr
    const char* gAt = batchbase + (chunk * 16 + fr) * 64 + sigma * 16;  // + s*16384
    const char* gAc = gAt + 128 * 64;
    // B: rows w*32+fr and w*32+16+fr (wave owns cols [w*32, w*32+32))
    const char* gB0 = batchbase + (w * 32 + fr) * 64 + sigma * 16;
    const char* gB1 = gB0 + 16 * 64;

    f32x4 accT0 = {0.f,0.f,0.f,0.f}, accT1 = {0.f,0.f,0.f,0.f};
    f32x4 accC0 = {0.f,0.f,0.f,0.f}, accC1 = {0.f,0.f,0.f,0.f};

    #pragma unroll
    for (int s = 0; s < 16; s++) {
        const size_t o = (size_t)s * 16384;
        const bf16x8 at = *(const bf16x8*)(gAt + o);
        const bf16x8 ac = *(const bf16x8*)(gAc + o);
        const bf16x8 b0 = *(const bf16x8*)(gB0 + o);
        const bf16x8 b1 = *(const bf16x8*)(gB1 + o);
        accT0 = __builtin_amdgcn_mfma_f32_16x16x32_bf16(at, b0, accT0, 0, 0, 0);
        accT1 = __builtin_amdgcn_mfma_f32_16x16x32_bf16(at, b1, accT1, 0, 0, 0);
        accC0 = __builtin_amdgcn_mfma_f32_16x16x32_bf16(ac, b0, accC0, 0, 0, 0);
        accC1 = __builtin_amdgcn_mfma_f32_16x16x32_bf16(ac, b1, accC1, 0, 0, 0);
    }

    float* P   = (float*)smem;                    // 32 x PSTR f32
    float* red = (float*)&smem[33280];

    // C/D layout (m89-verified): lane l, reg q -> row kg*4+q, col fr.
    // t-panel -> P rows 0..15, c-panel -> P rows 16..31; cols w*32 (+16).
    {
        const int rw = kg * 4;
        const int cw = w * 32 + fr;
        #pragma unroll
        for (int q = 0; q < 4; q++) P[(rw + q) * PSTR + cw]           = accT0[q];
        #pragma unroll
        for (int q = 0; q < 4; q++) P[(rw + q) * PSTR + cw + 16]      = accT1[q];
        #pragma unroll
        for (int q = 0; q < 4; q++) P[(16 + rw + q) * PSTR + cw]      = accC0[q];
        #pragma unroll
        for (int q = 0; q < 4; q++) P[(16 + rw + q) * PSTR + cw + 16] = accC1[q];
    }
    __syncthreads();

    // ---- Loss phase: 4 rows per wave, wave-private (verified rounds 3-19) --
    // rows 0..15 (t): pd = cols 0:128 (t.t), pn = cols 128:256 (t.c)
    // rows 16..31 (c): pd = cols 128:256 (c.c), pn = cols 0:128 (c.t)
    float wacc = 0.f;
    #pragma unroll
    for (int rr = 0; rr < 4; rr++) {
        const int r      = w * 4 + rr;
        const int pd_off = (r < 16) ? 0 : 128;
        const int pn_off = 128 - pd_off;
        float* prow = &P[r * PSTR];

        const float g0 = prow[pd_off + lane];
        const float g1 = prow[pd_off + lane + 64];
        float v0 = prow[pn_off + lane];
        float v1 = prow[pn_off + lane + 64];

        // bitonic sort ascending (2 elems/lane)
        #pragma unroll
        for (int kk = 2; kk <= 128; kk <<= 1) {
            if (kk == 128) {
                const float lo = fminf(v0, v1);
                const float hi = fmaxf(v0, v1);
                v0 = lo; v1 = hi;
            }
            #pragma unroll
            for (int j = (kk == 128 ? 32 : (kk >> 1)); j >= 1; j >>= 1) {
                const float p0 = __shfl_xor(v0, j, 64);
                const float p1 = __shfl_xor(v1, j, 64);
                const bool up0 = (lane & kk) == 0;
                const bool up1 = ((lane + 64) & kk) == 0;
                const bool lower = (lane & j) == 0;
                v0 = (up0 == lower) ? fminf(v0, p0) : fmaxf(v0, p0);
                v1 = (up1 == lower) ? fminf(v1, p1) : fmaxf(v1, p1);
            }
        }

        // inclusive prefix scans of the two halves
        float inc0 = v0, inc1 = v1;
        #pragma unroll
        for (int o = 1; o < 64; o <<= 1) {
            const float t0 = __shfl_up(inc0, o, 64);
            const float t1 = __shfl_up(inc1, o, 64);
            if (lane >= o) { inc0 += t0; inc1 += t1; }
        }
        const float tot0  = __shfl(inc0, 63, 64);
        const float total = tot0 + __shfl(inc1, 63, 64);

        // write sorted s[0:128] and exclusive prefix pre[0:129] in place
        prow[lane]            = v0;
        prow[64 + lane]       = v1;
        prow[130 + 1 + lane]  = inc0;
        prow[130 + 65 + lane] = tot0 + inc1;
        if (lane == 0) prow[130] = 0.f;

        // per-j: rank via guarded binary search, closed-form num/den
        #pragma unroll
        for (int h = 0; h < 2; h++) {
            const float g   = h ? g1 : g0;
            const float tau = g - 0.5f * ALPHA;   // v>0 <=> h_k > tau
            const float a   = ALPHA - 2.f * g;
            int pos = 0;
            #pragma unroll
            for (int st = 128; st > 0; st >>= 1) {
                const int nidx = pos + st;
                const float sv = prow[nidx - 1];
                pos = ((nidx <= 128) && (sv <= tau)) ? nidx : pos;
            }
            const float cnt = (float)(128 - pos);
            const float pre = prow[130 + pos];
            const float num = cnt * a + 2.f * (total - pre);
            wacc += num / (cnt + EPS);
        }
    }

    #pragma unroll
    for (int o = 32; o > 0; o >>= 1) wacc += __shfl_xor(wacc, o, 64);
    if (lane == 0) red[w] = wacc;
    __syncthreads();
    if (threadIdx.x == 0) {
        float s = 0.f;
        #pragma unroll
        for (int i = 0; i < 8; i++) s += red[i];
        part[p] = s;
        __threadfence();                          // release part[p]
        lastflag = atomicAdd(counter, 1);         // device-scope, 256 blocks
    }
    __syncthreads();

    // ---- Last block reduces all 256 partials -> out[0] (R8-verified) ------
    if (lastflag == 255) {
        __threadfence();                          // acquire
        float s = (threadIdx.x < 256) ? part[threadIdx.x] : 0.f;
        #pragma unroll
        for (int o = 32; o > 0; o >>= 1) s += __shfl_xor(s, o, 64);
        if (lane == 0) red[w] = s;
        __syncthreads();
        if (threadIdx.x == 0) {
            float t = 0.f;
            #pragma unroll
            for (int i = 0; i < 4; i++) t += red[i];
            out[0] = t * INV_CNT;
        }
    }
}

// ---------------------------------------------------------------------------
extern "C" void kernel_launch(void* const* d_in, const int* in_sizes, int n_in,
                              void* d_out, int out_size, void* d_ws, size_t ws_size,
                              hipStream_t stream) {
    const float* latent = (const float*)d_in[0];
    float* out  = (float*)d_out;
    char*  wsb  = (char*)d_ws;
    short* nrm2 = (short*)(wsb + NRM_OFF);
    float* part = (float*)(wsb + PART_OFF);
    int*   cnt  = (int*)(wsb + CNT_OFF);

    hipMemsetAsync(cnt, 0, sizeof(int), stream);  // capture-legal memset node
    hipLaunchKernelGGL(k_normalize, dim3(2048), dim3(256), 0, stream, latent, nrm2);
    hipLaunchKernelGGL(k_fused,     dim3(256),  dim3(512), 0, stream, nrm2, part, cnt, out);
}

// Round 21
// 29.234 us; speedup vs baseline: 1.2835x; 1.2835x over previous
//
#include <hip/hip_runtime.h>
#include <hip/hip_bf16.h>

// Problem constants
constexpr int   D      = 512;
constexpr float ALPHA  = 1.0f;
constexpr float EPS    = 1e-9f;
constexpr float INV_CNT = 1.0f / (32.0f * 128.0f * 128.0f);  // 1/524288

// ws layout (bytes)
constexpr size_t NRM_OFF  = 0;            // 8192*512*2 = 8388608 (bf16, k-major)
constexpr size_t PART_OFF = 8388608;      // 256*4

typedef short bf16x8 __attribute__((ext_vector_type(8)));
typedef float f32x4  __attribute__((ext_vector_type(4)));

// round-to-nearest-even f32 -> bf16 bits
__device__ __forceinline__ short f2bf(float f) {
    unsigned u = __builtin_bit_cast(unsigned, f);
    unsigned r = (u + 0x7FFFu + ((u >> 16) & 1u)) >> 16;
    return (short)r;
}

// nrm2 layout (k-major, slot-rotated), written by k_normalize:
//   byte(b, ks, row, slot) = ((b*16 + ks)*256 + row)*64 + slot*16
//   chunk c of row r stored at slot (c + (r>>1)) & 3

// ---------------------------------------------------------------------------
// K1: row-normalize fp32 -> bf16 into k-major rotated layout.
// (byte-identical to rounds 17-19: XCD-co-located row assignment -- block p
// on XCD p&7 writes rows (p&7)*1024 + (p>>3)*4 ..+4, so batch b is produced
// on XCD b>>2, the same XCD that consumes it in k_fused. R17: -2.2us.)
__global__ __launch_bounds__(256) void k_normalize(const float* __restrict__ in,
                                                   short* __restrict__ nrm2) {
    const int wid  = threadIdx.x >> 6;
    const int lane = threadIdx.x & 63;
    const int p    = blockIdx.x;
    const int r    = (p & 7) * 1024 + (p >> 3) * 4 + wid;   // global row 0..8191
    const int b    = r >> 8;
    const int row  = r & 255;
    const float4* src = (const float4*)(in + (size_t)r * D);
    float4 x0 = src[2 * lane];
    float4 x1 = src[2 * lane + 1];
    float ss = x0.x*x0.x + x0.y*x0.y + x0.z*x0.z + x0.w*x0.w
             + x1.x*x1.x + x1.y*x1.y + x1.z*x1.z + x1.w*x1.w;
    #pragma unroll
    for (int o = 32; o > 0; o >>= 1) ss += __shfl_xor(ss, o, 64);
    const float inv = rsqrtf(ss);
    bf16x8 v;                                     // elems 8*lane .. 8*lane+7
    v[0] = f2bf(x0.x * inv); v[1] = f2bf(x0.y * inv);
    v[2] = f2bf(x0.z * inv); v[3] = f2bf(x0.w * inv);
    v[4] = f2bf(x1.x * inv); v[5] = f2bf(x1.y * inv);
    v[6] = f2bf(x1.z * inv); v[7] = f2bf(x1.w * inv);
    const int ks   = lane >> 2;                   // k-slice 0..15
    const int slot = ((lane & 3) + (row >> 1)) & 3;
    char* dst = (char*)nrm2 + ((((size_t)b * 16 + ks) * 256 + row) * 64 + slot * 16);
    *(bf16x8*)dst = v;
}

// ---------------------------------------------------------------------------
// K2: FUSED gram+loss, MERGED HALVES. 256 blocks x 512 thr (8 waves).
// (byte-identical to round 19, best measured: 29.2us, absmax 0. R20's
// atomic-tail merge regressed +8.3us -- reverted.)
constexpr int PSTR = 260;

__global__ __launch_bounds__(512, 2) void k_fused(const short* __restrict__ nrm2,
                                                  float* __restrict__ part) {
    __shared__ __align__(16) char smem[33312];    // P 32x260 f32 = 33280; red @33280

    const int p     = blockIdx.x;
    const int slot  = p >> 3;                     // 0..31
    const int b     = (p & 7) * 4 + (slot & 3);   // XCD-bijective: 4 batches/XCD
    const int chunk = slot >> 2;                  // 0..7
    const int w     = threadIdx.x >> 6;           // 0..7
    const int lane  = threadIdx.x & 63;
    const int fr    = lane & 15;
    const int kg    = lane >> 4;

    const char* batchbase = (const char*)nrm2 + (size_t)b * 16 * 256 * 64;

    // slot rotation: all row terms (chunk*16, +128, w*32, +16) vanish mod 4
    const int sigma = (kg + (fr >> 1)) & 3;

    // A: t-row chunk*16+fr and c-row 128+chunk*16+fr
    const char* gAt = batchbase + (chunk * 16 + fr) * 64 + sigma * 16;  // + s*16384
    const char* gAc = gAt + 128 * 64;
    // B: rows w*32+fr and w*32+16+fr (wave owns cols [w*32, w*32+32))
    const char* gB0 = batchbase + (w * 32 + fr) * 64 + sigma * 16;
    const char* gB1 = gB0 + 16 * 64;

    f32x4 accT0 = {0.f,0.f,0.f,0.f}, accT1 = {0.f,0.f,0.f,0.f};
    f32x4 accC0 = {0.f,0.f,0.f,0.f}, accC1 = {0.f,0.f,0.f,0.f};

    #pragma unroll
    for (int s = 0; s < 16; s++) {
        const size_t o = (size_t)s * 16384;
        const bf16x8 at = *(const bf16x8*)(gAt + o);
        const bf16x8 ac = *(const bf16x8*)(gAc + o);
        const bf16x8 b0 = *(const bf16x8*)(gB0 + o);
        const bf16x8 b1 = *(const bf16x8*)(gB1 + o);
        accT0 = __builtin_amdgcn_mfma_f32_16x16x32_bf16(at, b0, accT0, 0, 0, 0);
        accT1 = __builtin_amdgcn_mfma_f32_16x16x32_bf16(at, b1, accT1, 0, 0, 0);
        accC0 = __builtin_amdgcn_mfma_f32_16x16x32_bf16(ac, b0, accC0, 0, 0, 0);
        accC1 = __builtin_amdgcn_mfma_f32_16x16x32_bf16(ac, b1, accC1, 0, 0, 0);
    }

    float* P   = (float*)smem;                    // 32 x PSTR f32
    float* red = (float*)&smem[33280];

    // C/D layout (m89-verified): lane l, reg q -> row kg*4+q, col fr.
    // t-panel -> P rows 0..15, c-panel -> P rows 16..31; cols w*32 (+16).
    {
        const int rw = kg * 4;
        const int cw = w * 32 + fr;
        #pragma unroll
        for (int q = 0; q < 4; q++) P[(rw + q) * PSTR + cw]           = accT0[q];
        #pragma unroll
        for (int q = 0; q < 4; q++) P[(rw + q) * PSTR + cw + 16]      = accT1[q];
        #pragma unroll
        for (int q = 0; q < 4; q++) P[(16 + rw + q) * PSTR + cw]      = accC0[q];
        #pragma unroll
        for (int q = 0; q < 4; q++) P[(16 + rw + q) * PSTR + cw + 16] = accC1[q];
    }
    __syncthreads();

    // ---- Loss phase: 4 rows per wave, wave-private (verified rounds 3-19) --
    // rows 0..15 (t): pd = cols 0:128 (t.t), pn = cols 128:256 (t.c)
    // rows 16..31 (c): pd = cols 128:256 (c.c), pn = cols 0:128 (c.t)
    float wacc = 0.f;
    #pragma unroll
    for (int rr = 0; rr < 4; rr++) {
        const int r      = w * 4 + rr;
        const int pd_off = (r < 16) ? 0 : 128;
        const int pn_off = 128 - pd_off;
        float* prow = &P[r * PSTR];

        const float g0 = prow[pd_off + lane];
        const float g1 = prow[pd_off + lane + 64];
        float v0 = prow[pn_off + lane];
        float v1 = prow[pn_off + lane + 64];

        // bitonic sort ascending (2 elems/lane)
        #pragma unroll
        for (int kk = 2; kk <= 128; kk <<= 1) {
            if (kk == 128) {
                const float lo = fminf(v0, v1);
                const float hi = fmaxf(v0, v1);
                v0 = lo; v1 = hi;
            }
            #pragma unroll
            for (int j = (kk == 128 ? 32 : (kk >> 1)); j >= 1; j >>= 1) {
                const float p0 = __shfl_xor(v0, j, 64);
                const float p1 = __shfl_xor(v1, j, 64);
                const bool up0 = (lane & kk) == 0;
                const bool up1 = ((lane + 64) & kk) == 0;
                const bool lower = (lane & j) == 0;
                v0 = (up0 == lower) ? fminf(v0, p0) : fmaxf(v0, p0);
                v1 = (up1 == lower) ? fminf(v1, p1) : fmaxf(v1, p1);
            }
        }

        // inclusive prefix scans of the two halves
        float inc0 = v0, inc1 = v1;
        #pragma unroll
        for (int o = 1; o < 64; o <<= 1) {
            const float t0 = __shfl_up(inc0, o, 64);
            const float t1 = __shfl_up(inc1, o, 64);
            if (lane >= o) { inc0 += t0; inc1 += t1; }
        }
        const float tot0  = __shfl(inc0, 63, 64);
        const float total = tot0 + __shfl(inc1, 63, 64);

        // write sorted s[0:128] and exclusive prefix pre[0:129] in place
        prow[lane]            = v0;
        prow[64 + lane]       = v1;
        prow[130 + 1 + lane]  = inc0;
        prow[130 + 65 + lane] = tot0 + inc1;
        if (lane == 0) prow[130] = 0.f;

        // per-j: rank via guarded binary search, closed-form num/den
        #pragma unroll
        for (int h = 0; h < 2; h++) {
            const float g   = h ? g1 : g0;
            const float tau = g - 0.5f * ALPHA;   // v>0 <=> h_k > tau
            const float a   = ALPHA - 2.f * g;
            int pos = 0;
            #pragma unroll
            for (int st = 128; st > 0; st >>= 1) {
                const int nidx = pos + st;
                const float sv = prow[nidx - 1];
                pos = ((nidx <= 128) && (sv <= tau)) ? nidx : pos;
            }
            const float cnt = (float)(128 - pos);
            const float pre = prow[130 + pos];
            const float num = cnt * a + 2.f * (total - pre);
            wacc += num / (cnt + EPS);
        }
    }

    #pragma unroll
    for (int o = 32; o > 0; o >>= 1) wacc += __shfl_xor(wacc, o, 64);
    if (lane == 0) red[w] = wacc;
    __syncthreads();
    if (threadIdx.x == 0) {
        float s = 0.f;
        #pragma unroll
        for (int i = 0; i < 8; i++) s += red[i];
        part[p] = s;
    }
}

// ---------------------------------------------------------------------------
// K3: final reduction of 256 partials -> scalar loss. 1 block x 256.
__global__ __launch_bounds__(256) void k_reduce(const float* __restrict__ part,
                                                float* __restrict__ out) {
    __shared__ float red[4];
    const int w    = threadIdx.x >> 6;
    const int lane = threadIdx.x & 63;
    float s = part[threadIdx.x];
    #pragma unroll
    for (int o = 32; o > 0; o >>= 1) s += __shfl_xor(s, o, 64);
    if (lane == 0) red[w] = s;
    __syncthreads();
    if (threadIdx.x == 0)
        out[0] = (red[0] + red[1] + red[2] + red[3]) * INV_CNT;
}

// ---------------------------------------------------------------------------
extern "C" void kernel_launch(void* const* d_in, const int* in_sizes, int n_in,
                              void* d_out, int out_size, void* d_ws, size_t ws_size,
                              hipStream_t stream) {
    const float* latent = (const float*)d_in[0];
    float* out  = (float*)d_out;
    char*  wsb  = (char*)d_ws;
    short* nrm2 = (short*)(wsb + NRM_OFF);
    float* part = (float*)(wsb + PART_OFF);

    hipLaunchKernelGGL(k_normalize, dim3(2048), dim3(256), 0, stream, latent, nrm2);
    hipLaunchKernelGGL(k_fused,     dim3(256),  dim3(512), 0, stream, nrm2, part);
    hipLaunchKernelGGL(k_reduce,    dim3(1),    dim3(256), 0, stream, part, out);
}

// Round 22
// 28.081 us; speedup vs baseline: 1.3362x; 1.0410x over previous
//
#include <hip/hip_runtime.h>
#include <hip/hip_bf16.h>

// Problem constants
constexpr int   D      = 512;
constexpr float ALPHA  = 1.0f;
constexpr float EPS    = 1e-9f;
constexpr float INV_CNT = 1.0f / (32.0f * 128.0f * 128.0f);  // 1/524288

// ws layout (bytes)
constexpr size_t NRM_OFF  = 0;            // 8192*512*2 = 8388608 (bf16, k-major)
constexpr size_t PART_OFF = 8388608;      // 256*4

typedef short bf16x8 __attribute__((ext_vector_type(8)));
typedef float f32x4  __attribute__((ext_vector_type(4)));

// round-to-nearest-even f32 -> bf16 bits
__device__ __forceinline__ short f2bf(float f) {
    unsigned u = __builtin_bit_cast(unsigned, f);
    unsigned r = (u + 0x7FFFu + ((u >> 16) & 1u)) >> 16;
    return (short)r;
}

// nrm2 layout (k-major, slot-rotated), written by k_normalize:
//   byte(b, ks, row, slot) = ((b*16 + ks)*256 + row)*64 + slot*16
//   chunk c of row r stored at slot (c + (r>>1)) & 3

// ---------------------------------------------------------------------------
// K1: row-normalize fp32 -> bf16 into k-major rotated layout.
// (byte-identical to rounds 17-21: XCD-co-located row assignment; R17 -2.2us)
__global__ __launch_bounds__(256) void k_normalize(const float* __restrict__ in,
                                                   short* __restrict__ nrm2) {
    const int wid  = threadIdx.x >> 6;
    const int lane = threadIdx.x & 63;
    const int p    = blockIdx.x;
    const int r    = (p & 7) * 1024 + (p >> 3) * 4 + wid;   // global row 0..8191
    const int b    = r >> 8;
    const int row  = r & 255;
    const float4* src = (const float4*)(in + (size_t)r * D);
    float4 x0 = src[2 * lane];
    float4 x1 = src[2 * lane + 1];
    float ss = x0.x*x0.x + x0.y*x0.y + x0.z*x0.z + x0.w*x0.w
             + x1.x*x1.x + x1.y*x1.y + x1.z*x1.z + x1.w*x1.w;
    #pragma unroll
    for (int o = 32; o > 0; o >>= 1) ss += __shfl_xor(ss, o, 64);
    const float inv = rsqrtf(ss);
    bf16x8 v;                                     // elems 8*lane .. 8*lane+7
    v[0] = f2bf(x0.x * inv); v[1] = f2bf(x0.y * inv);
    v[2] = f2bf(x0.z * inv); v[3] = f2bf(x0.w * inv);
    v[4] = f2bf(x1.x * inv); v[5] = f2bf(x1.y * inv);
    v[6] = f2bf(x1.z * inv); v[7] = f2bf(x1.w * inv);
    const int ks   = lane >> 2;                   // k-slice 0..15
    const int slot = ((lane & 3) + (row >> 1)) & 3;
    char* dst = (char*)nrm2 + ((((size_t)b * 16 + ks) * 256 + row) * 64 + slot * 16);
    *(bf16x8*)dst = v;
}

// ---------------------------------------------------------------------------
// K2: FUSED gram+loss, MERGED HALVES. 256 blocks x 1024 thr (16 waves).
// CHANGE vs R19/R21 (single variable): 16 waves instead of 8 at the same
// grid/work/LDS. grid=256 means 1 block/CU, so the loss phase previously ran
// only 2 waves/SIMD each with a 4-row x ~5Kcy serial chain (sort+scan+search)
// -- nearly unhidden latency. 16 waves -> 2 rows/wave (chain halved) and
// 4 waves/SIMD to interleave. Gram: wave owns 16 B-cols (2 A + 1 B load +
// 2 MFMA per step; same 1KB/wave contiguous coalescing; sigma unchanged
// since w*16 row terms vanish mod 4 after >>1). All arithmetic byte-level
// identical to R19 (absmax 0 rounds 3-21).
constexpr int PSTR = 260;

__global__ __launch_bounds__(1024, 4) void k_fused(const short* __restrict__ nrm2,
                                                   float* __restrict__ part) {
    __shared__ __align__(16) char smem[33408];    // P 32x260 f32 = 33280; red @33280

    const int p     = blockIdx.x;
    const int slot  = p >> 3;                     // 0..31
    const int b     = (p & 7) * 4 + (slot & 3);   // XCD-bijective: 4 batches/XCD
    const int chunk = slot >> 2;                  // 0..7
    const int w     = threadIdx.x >> 6;           // 0..15
    const int lane  = threadIdx.x & 63;
    const int fr    = lane & 15;
    const int kg    = lane >> 4;

    const char* batchbase = (const char*)nrm2 + (size_t)b * 16 * 256 * 64;

    // slot rotation: all row terms (chunk*16, +128, w*16, +fr base) vanish mod 4
    const int sigma = (kg + (fr >> 1)) & 3;

    // A: t-row chunk*16+fr and c-row 128+chunk*16+fr
    const char* gAt = batchbase + (chunk * 16 + fr) * 64 + sigma * 16;  // + s*16384
    const char* gAc = gAt + 128 * 64;
    // B: row w*16+fr (wave owns cols [w*16, w*16+16))
    const char* gB0 = batchbase + (w * 16 + fr) * 64 + sigma * 16;

    f32x4 accT = {0.f,0.f,0.f,0.f};
    f32x4 accC = {0.f,0.f,0.f,0.f};

    #pragma unroll
    for (int s = 0; s < 16; s++) {
        const size_t o = (size_t)s * 16384;
        const bf16x8 at = *(const bf16x8*)(gAt + o);
        const bf16x8 ac = *(const bf16x8*)(gAc + o);
        const bf16x8 b0 = *(const bf16x8*)(gB0 + o);
        accT = __builtin_amdgcn_mfma_f32_16x16x32_bf16(at, b0, accT, 0, 0, 0);
        accC = __builtin_amdgcn_mfma_f32_16x16x32_bf16(ac, b0, accC, 0, 0, 0);
    }

    float* P   = (float*)smem;                    // 32 x PSTR f32
    float* red = (float*)&smem[33280];            // 16 floats

    // C/D layout (m89-verified): lane l, reg q -> row kg*4+q, col fr.
    // t-panel -> P rows 0..15, c-panel -> P rows 16..31; cols w*16.
    {
        const int rw = kg * 4;
        const int cw = w * 16 + fr;
        #pragma unroll
        for (int q = 0; q < 4; q++) P[(rw + q) * PSTR + cw]      = accT[q];
        #pragma unroll
        for (int q = 0; q < 4; q++) P[(16 + rw + q) * PSTR + cw] = accC[q];
    }
    __syncthreads();

    // ---- Loss phase: 2 rows per wave, wave-private (verified rounds 3-21) --
    // rows 0..15 (t): pd = cols 0:128 (t.t), pn = cols 128:256 (t.c)
    // rows 16..31 (c): pd = cols 128:256 (c.c), pn = cols 0:128 (c.t)
    float wacc = 0.f;
    #pragma unroll
    for (int rr = 0; rr < 2; rr++) {
        const int r      = w * 2 + rr;
        const int pd_off = (r < 16) ? 0 : 128;
        const int pn_off = 128 - pd_off;
        float* prow = &P[r * PSTR];

        const float g0 = prow[pd_off + lane];
        const float g1 = prow[pd_off + lane + 64];
        float v0 = prow[pn_off + lane];
        float v1 = prow[pn_off + lane + 64];

        // bitonic sort ascending (2 elems/lane)
        #pragma unroll
        for (int kk = 2; kk <= 128; kk <<= 1) {
            if (kk == 128) {
                const float lo = fminf(v0, v1);
                const float hi = fmaxf(v0, v1);
                v0 = lo; v1 = hi;
            }
            #pragma unroll
            for (int j = (kk == 128 ? 32 : (kk >> 1)); j >= 1; j >>= 1) {
                const float p0 = __shfl_xor(v0, j, 64);
                const float p1 = __shfl_xor(v1, j, 64);
                const bool up0 = (lane & kk) == 0;
                const bool up1 = ((lane + 64) & kk) == 0;
                const bool lower = (lane & j) == 0;
                v0 = (up0 == lower) ? fminf(v0, p0) : fmaxf(v0, p0);
                v1 = (up1 == lower) ? fminf(v1, p1) : fmaxf(v1, p1);
            }
        }

        // inclusive prefix scans of the two halves
        float inc0 = v0, inc1 = v1;
        #pragma unroll
        for (int o = 1; o < 64; o <<= 1) {
            const float t0 = __shfl_up(inc0, o, 64);
            const float t1 = __shfl_up(inc1, o, 64);
            if (lane >= o) { inc0 += t0; inc1 += t1; }
        }
        const float tot0  = __shfl(inc0, 63, 64);
        const float total = tot0 + __shfl(inc1, 63, 64);

        // write sorted s[0:128] and exclusive prefix pre[0:129] in place
        prow[lane]            = v0;
        prow[64 + lane]       = v1;
        prow[130 + 1 + lane]  = inc0;
        prow[130 + 65 + lane] = tot0 + inc1;
        if (lane == 0) prow[130] = 0.f;

        // per-j: rank via guarded binary search, closed-form num/den
        #pragma unroll
        for (int h = 0; h < 2; h++) {
            const float g   = h ? g1 : g0;
            const float tau = g - 0.5f * ALPHA;   // v>0 <=> h_k > tau
            const float a   = ALPHA - 2.f * g;
            int pos = 0;
            #pragma unroll
            for (int st = 128; st > 0; st >>= 1) {
                const int nidx = pos + st;
                const float sv = prow[nidx - 1];
                pos = ((nidx <= 128) && (sv <= tau)) ? nidx : pos;
            }
            const float cnt = (float)(128 - pos);
            const float pre = prow[130 + pos];
            const float num = cnt * a + 2.f * (total - pre);
            wacc += num / (cnt + EPS);
        }
    }

    #pragma unroll
    for (int o = 32; o > 0; o >>= 1) wacc += __shfl_xor(wacc, o, 64);
    if (lane == 0) red[w] = wacc;
    __syncthreads();
    if (threadIdx.x == 0) {
        float s = 0.f;
        #pragma unroll
        for (int i = 0; i < 16; i++) s += red[i];
        part[p] = s;
    }
}

// ---------------------------------------------------------------------------
// K3: final reduction of 256 partials -> scalar loss. 1 block x 256.
__global__ __launch_bounds__(256) void k_reduce(const float* __restrict__ part,
                                                float* __restrict__ out) {
    __shared__ float red[4];
    const int w    = threadIdx.x >> 6;
    const int lane = threadIdx.x & 63;
    float s = part[threadIdx.x];
    #pragma unroll
    for (int o = 32; o > 0; o >>= 1) s += __shfl_xor(s, o, 64);
    if (lane == 0) red[w] = s;
    __syncthreads();
    if (threadIdx.x == 0)
        out[0] = (red[0] + red[1] + red[2] + red[3]) * INV_CNT;
}

// ---------------------------------------------------------------------------
extern "C" void kernel_launch(void* const* d_in, const int* in_sizes, int n_in,
                              void* d_out, int out_size, void* d_ws, size_t ws_size,
                              hipStream_t stream) {
    const float* latent = (const float*)d_in[0];
    float* out  = (float*)d_out;
    char*  wsb  = (char*)d_ws;
    short* nrm2 = (short*)(wsb + NRM_OFF);
    float* part = (float*)(wsb + PART_OFF);

    hipLaunchKernelGGL(k_normalize, dim3(2048), dim3(256),  0, stream, latent, nrm2);
    hipLaunchKernelGGL(k_fused,     dim3(256),  dim3(1024), 0, stream, nrm2, part);
    hipLaunchKernelGGL(k_reduce,    dim3(1),    dim3(256),  0, stream, part, out);
}

// Round 23
// 27.120 us; speedup vs baseline: 1.3836x; 1.0354x over previous
//
#include <hip/hip_runtime.h>
#include <hip/hip_bf16.h>

// Problem constants
constexpr int   D      = 512;
constexpr float ALPHA  = 1.0f;
constexpr float EPS    = 1e-9f;
constexpr float INV_CNT = 1.0f / (32.0f * 128.0f * 128.0f);  // 1/524288

// ws layout (bytes)
constexpr size_t NRM_OFF  = 0;            // 8192*512*2 = 8388608 (bf16, k-major)
constexpr size_t PART_OFF = 8388608;      // 512*4

typedef short bf16x8 __attribute__((ext_vector_type(8)));
typedef float f32x4  __attribute__((ext_vector_type(4)));

// round-to-nearest-even f32 -> bf16 bits
__device__ __forceinline__ short f2bf(float f) {
    unsigned u = __builtin_bit_cast(unsigned, f);
    unsigned r = (u + 0x7FFFu + ((u >> 16) & 1u)) >> 16;
    return (short)r;
}

// nrm2 layout (k-major, slot-rotated), written by k_normalize:
//   byte(b, ks, row, slot) = ((b*16 + ks)*256 + row)*64 + slot*16
//   chunk c of row r stored at slot (c + (r>>1)) & 3

// ---------------------------------------------------------------------------
// K1: row-normalize fp32 -> bf16 into k-major rotated layout.
// (byte-identical to rounds 17-22: XCD-co-located row assignment; R17 -2.2us)
__global__ __launch_bounds__(256) void k_normalize(const float* __restrict__ in,
                                                   short* __restrict__ nrm2) {
    const int wid  = threadIdx.x >> 6;
    const int lane = threadIdx.x & 63;
    const int p    = blockIdx.x;
    const int r    = (p & 7) * 1024 + (p >> 3) * 4 + wid;   // global row 0..8191
    const int b    = r >> 8;
    const int row  = r & 255;
    const float4* src = (const float4*)(in + (size_t)r * D);
    float4 x0 = src[2 * lane];
    float4 x1 = src[2 * lane + 1];
    float ss = x0.x*x0.x + x0.y*x0.y + x0.z*x0.z + x0.w*x0.w
             + x1.x*x1.x + x1.y*x1.y + x1.z*x1.z + x1.w*x1.w;
    #pragma unroll
    for (int o = 32; o > 0; o >>= 1) ss += __shfl_xor(ss, o, 64);
    const float inv = rsqrtf(ss);
    bf16x8 v;                                     // elems 8*lane .. 8*lane+7
    v[0] = f2bf(x0.x * inv); v[1] = f2bf(x0.y * inv);
    v[2] = f2bf(x0.z * inv); v[3] = f2bf(x0.w * inv);
    v[4] = f2bf(x1.x * inv); v[5] = f2bf(x1.y * inv);
    v[6] = f2bf(x1.z * inv); v[7] = f2bf(x1.w * inv);
    const int ks   = lane >> 2;                   // k-slice 0..15
    const int slot = ((lane & 3) + (row >> 1)) & 3;
    char* dst = (char*)nrm2 + ((((size_t)b * 16 + ks) * 256 + row) * 64 + slot * 16);
    *(bf16x8*)dst = v;
}

// ---------------------------------------------------------------------------
// K2: FUSED gram+loss, 16-row panels at 2 blocks/CU. 512 blocks x 1024 thr.
// CHANGE vs R22 (single variable set): back to 16-row A-panels (R18 mapping)
// so LDS=16.7KB and __launch_bounds__(1024,8) allows 2 CO-RESIDENT blocks/CU
// (8 waves/SIMD): generation-2's gram (VMEM/MFMA) overlaps generation-1's
// loss (LDS/VALU) on the same CU, and loss drops to 1 ROW PER WAVE (serial
// chain halved again; pd_off now block-uniform). Gram per wave: 1 A-load +
// 1 B-load + 1 MFMA per k-step (direct global->VGPR, R18-verified
// coalescing). All arithmetic byte-identical (absmax 0 rounds 3-22).
constexpr int PSTR = 260;

__global__ __launch_bounds__(1024, 8) void k_fused(const short* __restrict__ nrm2,
                                                   float* __restrict__ part) {
    __shared__ __align__(16) char smem[16768];    // P 16x260 f32 = 16640; red @16640

    const int p     = blockIdx.x;
    const int slot  = p >> 3;                     // 0..63
    const int b     = (p & 7) * 4 + (slot & 3);   // XCD-bijective: 4 batches/XCD
    const int rem   = slot >> 2;                  // 0..15
    const int chunk = rem & 7;
    const int half  = rem >> 3;
    const int w     = threadIdx.x >> 6;           // 0..15
    const int lane  = threadIdx.x & 63;
    const int fr    = lane & 15;
    const int kg    = lane >> 4;

    const char* batchbase = (const char*)nrm2 + (size_t)b * 16 * 256 * 64;

    // slot rotation: row terms (half*128, chunk*16, w*16) vanish mod 4
    const int sigma = (kg + (fr >> 1)) & 3;

    // A: row half*128 + chunk*16 + fr
    const char* gA = batchbase + (half * 128 + chunk * 16 + fr) * 64 + sigma * 16;
    // B: row w*16 + fr (wave owns cols [w*16, w*16+16))
    const char* gB = batchbase + (w * 16 + fr) * 64 + sigma * 16;

    f32x4 acc = {0.f, 0.f, 0.f, 0.f};

    #pragma unroll
    for (int s = 0; s < 16; s++) {
        const size_t o = (size_t)s * 16384;
        const bf16x8 a  = *(const bf16x8*)(gA + o);
        const bf16x8 b0 = *(const bf16x8*)(gB + o);
        acc = __builtin_amdgcn_mfma_f32_16x16x32_bf16(a, b0, acc, 0, 0, 0);
    }

    float* P   = (float*)smem;                    // 16 x PSTR f32
    float* red = (float*)&smem[16640];            // 16 floats

    // C/D layout (m89-verified): lane l, reg q -> row kg*4+q, col fr
    {
        const int rw = kg * 4;
        const int cw = w * 16 + fr;
        #pragma unroll
        for (int q = 0; q < 4; q++) P[(rw + q) * PSTR + cw] = acc[q];
    }
    __syncthreads();

    // ---- Loss phase: ONE row per wave (r = w), block-uniform pd_off --------
    // half=0 (t-rows): pd = cols 0:128 (t.t), pn = cols 128:256 (t.c)
    // half=1 (c-rows): pd = cols 128:256 (c.c), pn = cols 0:128 (c.t)
    const int pd_off = half ? 128 : 0;
    const int pn_off = 128 - pd_off;
    float* prow = &P[w * PSTR];

    const float g0 = prow[pd_off + lane];
    const float g1 = prow[pd_off + lane + 64];
    float v0 = prow[pn_off + lane];
    float v1 = prow[pn_off + lane + 64];

    // bitonic sort ascending (2 elems/lane)
    #pragma unroll
    for (int kk = 2; kk <= 128; kk <<= 1) {
        if (kk == 128) {
            const float lo = fminf(v0, v1);
            const float hi = fmaxf(v0, v1);
            v0 = lo; v1 = hi;
        }
        #pragma unroll
        for (int j = (kk == 128 ? 32 : (kk >> 1)); j >= 1; j >>= 1) {
            const float p0 = __shfl_xor(v0, j, 64);
            const float p1 = __shfl_xor(v1, j, 64);
            const bool up0 = (lane & kk) == 0;
            const bool up1 = ((lane + 64) & kk) == 0;
            const bool lower = (lane & j) == 0;
            v0 = (up0 == lower) ? fminf(v0, p0) : fmaxf(v0, p0);
            v1 = (up1 == lower) ? fminf(v1, p1) : fmaxf(v1, p1);
        }
    }

    // inclusive prefix scans of the two halves
    float inc0 = v0, inc1 = v1;
    #pragma unroll
    for (int o = 1; o < 64; o <<= 1) {
        const float t0 = __shfl_up(inc0, o, 64);
        const float t1 = __shfl_up(inc1, o, 64);
        if (lane >= o) { inc0 += t0; inc1 += t1; }
    }
    const float tot0  = __shfl(inc0, 63, 64);
    const float total = tot0 + __shfl(inc1, 63, 64);

    // write sorted s[0:128] and exclusive prefix pre[0:129] in place
    prow[lane]            = v0;
    prow[64 + lane]       = v1;
    prow[130 + 1 + lane]  = inc0;
    prow[130 + 65 + lane] = tot0 + inc1;
    if (lane == 0) prow[130] = 0.f;

    // per-j: rank via guarded binary search, closed-form num/den
    float wacc = 0.f;
    #pragma unroll
    for (int h = 0; h < 2; h++) {
        const float g   = h ? g1 : g0;
        const float tau = g - 0.5f * ALPHA;       // v>0 <=> h_k > tau
        const float a   = ALPHA - 2.f * g;
        int pos = 0;
        #pragma unroll
        for (int st = 128; st > 0; st >>= 1) {
            const int nidx = pos + st;
            const float sv = prow[nidx - 1];
            pos = ((nidx <= 128) && (sv <= tau)) ? nidx : pos;
        }
        const float cnt = (float)(128 - pos);
        const float pre = prow[130 + pos];
        const float num = cnt * a + 2.f * (total - pre);
        wacc += num / (cnt + EPS);
    }

    #pragma unroll
    for (int o = 32; o > 0; o >>= 1) wacc += __shfl_xor(wacc, o, 64);
    if (lane == 0) red[w] = wacc;
    __syncthreads();
    if (threadIdx.x == 0) {
        float s = 0.f;
        #pragma unroll
        for (int i = 0; i < 16; i++) s += red[i];
        part[p] = s;
    }
}

// ---------------------------------------------------------------------------
// K3: final reduction of 512 partials -> scalar loss. 1 block x 512.
__global__ __launch_bounds__(512) void k_reduce(const float* __restrict__ part,
                                                float* __restrict__ out) {
    __shared__ float red[8];
    const int w    = threadIdx.x >> 6;
    const int lane = threadIdx.x & 63;
    float s = part[threadIdx.x];
    #pragma unroll
    for (int o = 32; o > 0; o >>= 1) s += __shfl_xor(s, o, 64);
    if (lane == 0) red[w] = s;
    __syncthreads();
    if (threadIdx.x == 0) {
        float t = 0.f;
        #pragma unroll
        for (int i = 0; i < 8; i++) t += red[i];
        out[0] = t * INV_CNT;
    }
}

// ---------------------------------------------------------------------------
extern "C" void kernel_launch(void* const* d_in, const int* in_sizes, int n_in,
                              void* d_out, int out_size, void* d_ws, size_t ws_size,
                              hipStream_t stream) {
    const float* latent = (const float*)d_in[0];
    float* out  = (float*)d_out;
    char*  wsb  = (char*)d_ws;
    short* nrm2 = (short*)(wsb + NRM_OFF);
    float* part = (float*)(wsb + PART_OFF);

    hipLaunchKernelGGL(k_normalize, dim3(2048), dim3(256),  0, stream, latent, nrm2);
    hipLaunchKernelGGL(k_fused,     dim3(512),  dim3(1024), 0, stream, nrm2, part);
    hipLaunchKernelGGL(k_reduce,    dim3(1),    dim3(512),  0, stream, part, out);
}